// Round 19
// baseline (103.880 us; speedup 1.0000x reference)
//
#include <hip/hip_runtime.h>
#include <hip/hip_bf16.h>

typedef short bf16x8 __attribute__((ext_vector_type(8)));
typedef float f32x4  __attribute__((ext_vector_type(4)));

typedef __attribute__((address_space(3))) void lds_t;
typedef __attribute__((address_space(1))) void gbl_t;

#define MFMA16(a,b,c) __builtin_amdgcn_mfma_f32_16x16x32_bf16((a),(b),(c),0,0,0)

__device__ __forceinline__ unsigned short f2bf(float f) {
    __hip_bfloat16 h = __float2bfloat16(f);
    return __builtin_bit_cast(unsigned short, h);
}
__device__ __forceinline__ float bf2f(unsigned short u) {
    __hip_bfloat16 h = __builtin_bit_cast(__hip_bfloat16, u);
    return __bfloat162float(h);
}

// ============================================================================
// Fused prep (R15, unchanged): x -> A1h, w_qkv (einops permute) -> W1h,
// w_out -> W3h.  All bf16 hi-only compact, float4-vectorized, grid-stride.
// ============================================================================
__global__ void prep_all(const float* __restrict__ x,
                         const float* __restrict__ w_qkv,
                         const float* __restrict__ w_out,
                         unsigned short* __restrict__ A1h,
                         unsigned short* __restrict__ W1h,
                         unsigned short* __restrict__ W3h) {
    const int NX = 4096 * 256, NW1 = 3072 * 256, NW3 = 1024 * 256;
    for (int idx = blockIdx.x * blockDim.x + threadIdx.x; idx < NX + NW1 + NW3;
         idx += gridDim.x * blockDim.x) {
        if (idx < NX) {
            int base = idx * 4;
            float4 v = *reinterpret_cast<const float4*>(x + base);
            ushort4 hi;
            hi.x = f2bf(v.x); hi.y = f2bf(v.y);
            hi.z = f2bf(v.z); hi.w = f2bf(v.w);
            *reinterpret_cast<ushort4*>(A1h + base) = hi;
        } else if (idx < NX + NW1) {
            int base = (idx - NX) * 4;
            int n = base >> 10, c = base & 1023;
            int d = n & 63, which = n >> 10, h = (n >> 6) & 15;
            int srow = d * 48 + which * 16 + h;
            float4 v =
                *reinterpret_cast<const float4*>(w_qkv + (size_t)srow * 1024 + c);
            ushort4 hi;
            hi.x = f2bf(v.x); hi.y = f2bf(v.y);
            hi.z = f2bf(v.z); hi.w = f2bf(v.w);
            *reinterpret_cast<ushort4*>(W1h + (size_t)n * 1024 + c) = hi;
        } else {
            int base = (idx - NX - NW1) * 4;
            float4 v = *reinterpret_cast<const float4*>(w_out + base);
            ushort4 hi;
            hi.x = f2bf(v.x); hi.y = f2bf(v.y);
            hi.z = f2bf(v.z); hi.w = f2bf(v.w);
            *reinterpret_cast<ushort4*>(W3h + base) = hi;
        }
    }
}

// ============================================================================
// QKV GEMM v6 (R17, unchanged — measured ~29us): BK=64, 16 steps, 64 MFMA/
// step/wave, 128KB 2-slot dbuf, XOR swizzle, grid (12,16), 8 waves.
// ============================================================================
__global__ __launch_bounds__(512, 1) void gemm256_hi(
    const unsigned short* __restrict__ A, const unsigned short* __restrict__ B,
    unsigned short* __restrict__ outQ, unsigned short* __restrict__ outK,
    unsigned short* __restrict__ outV) {
    __shared__ unsigned short lds[65536];
    const int tid = threadIdx.x;
    const int wid = tid >> 6, lane = tid & 63;
    const int lrow = lane & 15, lgrp = lane >> 4;
    const int wr = wid >> 2, wc = wid & 3;
    const int mtile = blockIdx.y * 256, ntile = blockIdx.x * 256;

    const int csw0 = (lgrp ^ (lrow & 7)) * 8;
    const int csw1 = ((4 | lgrp) ^ (lrow & 7)) * 8;
    const int arowb = (wr * 128 + lrow) * 64;
    const int browb = (wc * 64 + lrow) * 64;

    const int srow = tid >> 3;
    const int schunk = tid & 7;
    const int gchunk = schunk ^ (srow & 7);
    const unsigned short* Abase = A + (size_t)(mtile + srow) * 1024 + gchunk * 8;
    const unsigned short* Bbase = B + (size_t)(ntile + srow) * 1024 + gchunk * 8;
    const int sdst = srow * 64 + schunk * 8;

    f32x4 acc[8][4];
#pragma unroll
    for (int i = 0; i < 8; ++i)
#pragma unroll
        for (int j = 0; j < 4; ++j) {
            f32x4 z = {0.f, 0.f, 0.f, 0.f};
            acc[i][j] = z;
        }

#pragma unroll
    for (int e = 0; e < 4; ++e)
        __builtin_amdgcn_global_load_lds(
            (const gbl_t*)(Abase + (size_t)e * 64 * 1024),
            (lds_t*)(lds + e * 4096 + sdst), 16, 0, 0);
#pragma unroll
    for (int e = 0; e < 4; ++e)
        __builtin_amdgcn_global_load_lds(
            (const gbl_t*)(Bbase + (size_t)e * 64 * 1024),
            (lds_t*)(lds + 32768 + e * 4096 + sdst), 16, 0, 0);
    asm volatile("s_waitcnt vmcnt(0)" ::: "memory");
    __syncthreads();

    for (int s = 0; s < 16; ++s) {
        const int cur = s & 1;
        const unsigned short* abuf = lds + cur * 16384;
        const unsigned short* bbuf = lds + 32768 + cur * 16384;
        const int nx = cur ^ 1;
        const int kb = (s + 1) * 64;

        if (s < 15) {
#pragma unroll
            for (int e = 0; e < 4; ++e)
                __builtin_amdgcn_global_load_lds(
                    (const gbl_t*)(Abase + (size_t)e * 64 * 1024 + kb),
                    (lds_t*)(lds + nx * 16384 + e * 4096 + sdst), 16, 0, 0);
        }
        {
            bf16x8 af[8], bfv[4];
#pragma unroll
            for (int i = 0; i < 8; ++i)
                af[i] = *reinterpret_cast<const bf16x8*>(abuf + arowb + i * 1024 +
                                                         csw0);
#pragma unroll
            for (int j = 0; j < 4; ++j)
                bfv[j] = *reinterpret_cast<const bf16x8*>(bbuf + browb +
                                                          j * 1024 + csw0);
            __builtin_amdgcn_s_setprio(1);
#pragma unroll
            for (int i = 0; i < 8; ++i)
#pragma unroll
                for (int j = 0; j < 4; ++j)
                    acc[i][j] = MFMA16(af[i], bfv[j], acc[i][j]);
            __builtin_amdgcn_s_setprio(0);
        }
        if (s < 15) {
#pragma unroll
            for (int e = 0; e < 4; ++e)
                __builtin_amdgcn_global_load_lds(
                    (const gbl_t*)(Bbase + (size_t)e * 64 * 1024 + kb),
                    (lds_t*)(lds + 32768 + nx * 16384 + e * 4096 + sdst), 16, 0,
                    0);
        }
        {
            bf16x8 af[8], bfv[4];
#pragma unroll
            for (int i = 0; i < 8; ++i)
                af[i] = *reinterpret_cast<const bf16x8*>(abuf + arowb + i * 1024 +
                                                         csw1);
#pragma unroll
            for (int j = 0; j < 4; ++j)
                bfv[j] = *reinterpret_cast<const bf16x8*>(bbuf + browb +
                                                          j * 1024 + csw1);
            __builtin_amdgcn_s_setprio(1);
#pragma unroll
            for (int i = 0; i < 8; ++i)
#pragma unroll
                for (int j = 0; j < 4; ++j)
                    acc[i][j] = MFMA16(af[i], bfv[j], acc[i][j]);
            __builtin_amdgcn_s_setprio(0);
        }

        if (s < 15) {
            asm volatile("s_waitcnt vmcnt(0)" ::: "memory");
            __syncthreads();
        }
    }

#pragma unroll
    for (int i = 0; i < 8; ++i) {
#pragma unroll
        for (int j = 0; j < 4; ++j) {
#pragma unroll
            for (int r = 0; r < 4; ++r) {
                float v = acc[i][j][r];
                int m = mtile + wr * 128 + i * 16 + lgrp * 4 + r;
                int n = ntile + wc * 64 + j * 16 + lrow;
                int which = n >> 10;
                int hh = (n >> 6) & 15;
                int d = n & 63;
                int b = m >> 10, t = m & 1023;
                unsigned short* dstp =
                    (which == 0) ? outQ : ((which == 1) ? outK : outV);
                dstp[((size_t)((b << 4) + hh) * 1024 + t) * 64 + d] = f2bf(v);
            }
        }
    }
}

// ============================================================================
// Out-projection GEMM v5 (R16, unchanged — measured ~14us): BK=64, 16 steps,
// tile 64x128, 4 waves, 2-slot dbuf 48KB, XOR swizzle, XCD swizzle.
// ============================================================================
__global__ __launch_bounds__(256, 3) void gemm_out_v5(
    const unsigned short* __restrict__ A, const unsigned short* __restrict__ B,
    float* __restrict__ outF) {
    __shared__ unsigned short As[2][64 * 64];   // 16 KB
    __shared__ unsigned short Bs[2][128 * 64];  // 32 KB
    const int tid = threadIdx.x;
    const int wid = tid >> 6, lane = tid & 63;
    const int lrow = lane & 15, lgrp = lane >> 4;
    const int wr = wid >> 1, wc = wid & 1;
    const int h = blockIdx.x;
    const int xcd = h & 7, within = h >> 3;
    const int mtile = (xcd * 8 + (within & 7)) * 64;
    const int ntile = (within >> 3) * 128;

    const int srow = tid >> 3;
    const int schunk = (tid & 7) ^ (srow & 7);
    const unsigned short* Abase = A + (size_t)(mtile + srow) * 1024 + schunk * 8;
    const unsigned short* Bbase = B + (size_t)(ntile + srow) * 1024 + schunk * 8;

    const int csw0 = (lgrp ^ (lrow & 7)) * 8;
    const int csw1 = ((4 | lgrp) ^ (lrow & 7)) * 8;
    const int arow = wr * 32 + lrow;
    const int brow = wc * 64 + lrow;

    f32x4 acc[2][4];
#pragma unroll
    for (int i = 0; i < 2; ++i)
#pragma unroll
        for (int j = 0; j < 4; ++j) {
            f32x4 z = {0.f, 0.f, 0.f, 0.f};
            acc[i][j] = z;
        }

#pragma unroll
    for (int e = 0; e < 2; ++e)
        __builtin_amdgcn_global_load_lds(
            (const gbl_t*)(Abase + (size_t)e * 32 * 1024),
            (lds_t*)(&As[0][0] + e * 2048 + tid * 8), 16, 0, 0);
#pragma unroll
    for (int e = 0; e < 4; ++e)
        __builtin_amdgcn_global_load_lds(
            (const gbl_t*)(Bbase + (size_t)e * 32 * 1024),
            (lds_t*)(&Bs[0][0] + e * 2048 + tid * 8), 16, 0, 0);
    asm volatile("s_waitcnt vmcnt(0)" ::: "memory");
    __syncthreads();

    for (int s = 0; s < 16; ++s) {
        const int cur = s & 1;
        if (s < 15) {
            const int kb = (s + 1) * 64;
            const int nx = cur ^ 1;
#pragma unroll
            for (int e = 0; e < 2; ++e)
                __builtin_amdgcn_global_load_lds(
                    (const gbl_t*)(Abase + (size_t)e * 32 * 1024 + kb),
                    (lds_t*)(&As[nx][0] + e * 2048 + tid * 8), 16, 0, 0);
#pragma unroll
            for (int e = 0; e < 4; ++e)
                __builtin_amdgcn_global_load_lds(
                    (const gbl_t*)(Bbase + (size_t)e * 32 * 1024 + kb),
                    (lds_t*)(&Bs[nx][0] + e * 2048 + tid * 8), 16, 0, 0);
        }
        bf16x8 a0[2], a1[2], b0[4], b1[4];
#pragma unroll
        for (int i = 0; i < 2; ++i) {
            a0[i] = *reinterpret_cast<const bf16x8*>(&As[cur][0] +
                                                     (arow + i * 16) * 64 + csw0);
            a1[i] = *reinterpret_cast<const bf16x8*>(&As[cur][0] +
                                                     (arow + i * 16) * 64 + csw1);
        }
#pragma unroll
        for (int j = 0; j < 4; ++j) {
            b0[j] = *reinterpret_cast<const bf16x8*>(&Bs[cur][0] +
                                                     (brow + j * 16) * 64 + csw0);
            b1[j] = *reinterpret_cast<const bf16x8*>(&Bs[cur][0] +
                                                     (brow + j * 16) * 64 + csw1);
        }
        __builtin_amdgcn_s_setprio(1);
#pragma unroll
        for (int i = 0; i < 2; ++i)
#pragma unroll
            for (int j = 0; j < 4; ++j) {
                acc[i][j] = MFMA16(a0[i], b0[j], acc[i][j]);
                acc[i][j] = MFMA16(a1[i], b1[j], acc[i][j]);
            }
        __builtin_amdgcn_s_setprio(0);
        if (s < 15) {
            asm volatile("s_waitcnt vmcnt(0)" ::: "memory");
            __syncthreads();
        }
    }

#pragma unroll
    for (int i = 0; i < 2; ++i)
#pragma unroll
        for (int j = 0; j < 4; ++j)
#pragma unroll
            for (int r = 0; r < 4; ++r) {
                int m = mtile + wr * 32 + i * 16 + lgrp * 4 + r;
                int n = ntile + wc * 64 + j * 16 + lrow;
                outF[(size_t)m * 1024 + n] = acc[i][j][r];
            }
}

// V [bh][1024][64] -> V^T [bh][64][1024], LDS-tiled, coalesced both sides.
__global__ __launch_bounds__(256) void transpose_v(
    const unsigned short* __restrict__ Vb, unsigned short* __restrict__ Vtg) {
    __shared__ unsigned short L[64][72];
    const int tt = blockIdx.x, bh = blockIdx.y;
    const int tid = threadIdx.x;
#pragma unroll
    for (int e = 0; e < 2; ++e) {
        int chunk = e * 256 + tid;
        int r = chunk >> 3, c = (chunk & 7) * 8;
        uint4 v = *reinterpret_cast<const uint4*>(
            Vb + ((size_t)bh * 1024 + tt * 64 + r) * 64 + c);
        *reinterpret_cast<uint4*>(&L[r][c]) = v;
    }
    __syncthreads();
#pragma unroll
    for (int e = 0; e < 2; ++e) {
        int chunk = e * 256 + tid;
        int d = chunk >> 3, t0 = (chunk & 7) * 8;
        unsigned short tmp[8];
#pragma unroll
        for (int u = 0; u < 8; ++u) tmp[u] = L[t0 + u][d];
        *reinterpret_cast<uint4*>(Vtg + ((size_t)bh * 64 + d) * 1024 + tt * 64 +
                                  t0) = *reinterpret_cast<const uint4*>(tmp);
    }
}

// ============================================================================
// Flash attention R19: QBLK 128 -> 256 (4th application of the step-halving
// law: R11-, R16+, R17+).  grid (64,4) = 256 blocks = 1 round/CU (was 2);
// per-CU staging/drain/barrier rounds HALVE at constant per-element math.
// Each wave processes TWO 16-row q-slices (ih=0,1) per staged K/V tile;
// K/V global re-reads halve (4 q-blocks/bh).  Per-slice math byte-identical
// (swapped QK^T, exp2 softmax, defer-max per slice, cvt_pk pack, PV).
// Ps gets 2 per-wave sections (32 KB); bias strip 1280.  LDS 69 KB.
// XCD locality kept: flat = bh + 64*qt -> XCD = bh%8.
// ============================================================================
__global__ __launch_bounds__(512) void attn_kernel(
    const unsigned short* __restrict__ Qb, const unsigned short* __restrict__ Kb,
    const unsigned short* __restrict__ Vtg, const float* __restrict__ rel_bias,
    unsigned short* __restrict__ A3) {
    const int bh = blockIdx.x;  // 0..63  (XCD = bh%8)
    const int qt = blockIdx.y;  // 0..3 (256 q-rows each)
    const int b = bh >> 4, h = bh & 15;
    const int tid = threadIdx.x;
    const int w = tid >> 6, lane = tid & 63;  // w in 0..7
    const int lrow = lane & 15, lgrp = lane >> 4;
    const float LOG2E = 1.4426950408889634f;
    const float SCALE2 = 0.125f * 1.4426950408889634f;
    const float THR = 11.5f;  // ~8 nats in exp2 units

    __shared__ unsigned short Ks[2][64 * 64];   // 16 KB
    __shared__ unsigned short Vs[2][64 * 64];   // 16 KB
    __shared__ unsigned short Ps[8][2 * 1024];  // 32 KB (2 sections/wave)
    __shared__ float BiasF[1280];               // 5 KB, staged once

    const unsigned short* Ktile = Kb + (size_t)bh * 1024 * 64;
    const unsigned short* Vtile = Vtg + (size_t)bh * 64 * 1024;

    // two q-slices per wave: rows qt*256 + ih*128 + w*16 + lrow
    bf16x8 qa[2][2];
#pragma unroll
    for (int ih = 0; ih < 2; ++ih) {
        const unsigned short* Qp =
            Qb + ((size_t)bh * 1024 + qt * 256 + ih * 128 + w * 16 + lrow) * 64;
        qa[ih][0] = *reinterpret_cast<const bf16x8*>(Qp + lgrp * 8);
        qa[ih][1] = *reinterpret_cast<const bf16x8*>(Qp + 32 + lgrp * 8);
    }

    const int sr0 = w * 8 + (lane >> 3);
    const int sc_lo = lane & 7;

    float m_run[2] = {-3.0e38f, -3.0e38f};
    float l_run[2] = {0.f, 0.f};
    f32x4 o_acc[2][4];
#pragma unroll
    for (int ih = 0; ih < 2; ++ih)
#pragma unroll
        for (int n = 0; n < 4; n++) {
            f32x4 z = {0.f, 0.f, 0.f, 0.f};
            o_acc[ih][n] = z;
        }

    // BiasF[v], v = j - iloc + 255, iloc in [0,256): v in [0,1278].
    // rel row = v + rbase, rbase = 768 - qt*256 in [0,768]; max 2046.
    const int bbase0 = lgrp * 4 + 255 - w * 16 - lrow;  // ih=0; ih=1: -128

    {
        {
            int r = sr0;
            int c = sc_lo ^ (r & 7);
            __builtin_amdgcn_global_load_lds(
                (const gbl_t*)(Ktile + (size_t)r * 64 + c * 8),
                (lds_t*)(&Ks[0][0] + w * 512), 16, 0, 0);
            __builtin_amdgcn_global_load_lds(
                (const gbl_t*)(Vtile + (size_t)r * 1024 + c * 8),
                (lds_t*)(&Vs[0][0] + w * 512), 16, 0, 0);
        }
        const int rbase = 768 - qt * 256;
        for (int t = tid; t < 1279; t += 512)
            BiasF[t] = rel_bias[(size_t)(t + rbase) * 16 + h] * LOG2E;
        asm volatile("s_waitcnt vmcnt(0)" ::: "memory");
        __syncthreads();
    }

    for (int kv = 0; kv < 16; ++kv) {
        const int cur = kv & 1;
        const int j0 = kv * 64;
        if (kv < 15) {
            const int j0n = (kv + 1) * 64;
            int r = sr0;
            int c = sc_lo ^ (r & 7);
            __builtin_amdgcn_global_load_lds(
                (const gbl_t*)(Ktile + (size_t)(j0n + r) * 64 + c * 8),
                (lds_t*)(&Ks[cur ^ 1][0] + w * 512), 16, 0, 0);
            __builtin_amdgcn_global_load_lds(
                (const gbl_t*)(Vtile + (size_t)r * 1024 + j0n + c * 8),
                (lds_t*)(&Vs[cur ^ 1][0] + w * 512), 16, 0, 0);
        }

        const unsigned short* kbuf = &Ks[cur][0];
        const unsigned short* vbuf = &Vs[cur][0];

#pragma unroll
        for (int ih = 0; ih < 2; ++ih) {
            // ---- S^T = K Q^T for slice ih ----
            f32x4 s[4];
            __builtin_amdgcn_s_setprio(1);
#pragma unroll
            for (int f = 0; f < 4; ++f) {
                int krow = f * 16 + lrow;
                int sw0 = (lgrp ^ (lrow & 7)) * 8;
                int sw1 = ((4 | lgrp) ^ (lrow & 7)) * 8;
                bf16x8 kb0 =
                    *reinterpret_cast<const bf16x8*>(kbuf + krow * 64 + sw0);
                bf16x8 kb1 =
                    *reinterpret_cast<const bf16x8*>(kbuf + krow * 64 + sw1);
                f32x4 z = {0.f, 0.f, 0.f, 0.f};
                z = MFMA16(kb0, qa[ih][0], z);
                z = MFMA16(kb1, qa[ih][1], z);
                s[f] = z;
            }
            __builtin_amdgcn_s_setprio(0);

            // ---- softmax, row-local (exp2 domain) ----
            const int bb = j0 + bbase0 - ih * 128;
            float x[4][4];
            float pm = -3.0e38f;
#pragma unroll
            for (int f = 0; f < 4; ++f)
#pragma unroll
                for (int r = 0; r < 4; ++r) {
                    float xv = s[f][r] * SCALE2 + BiasF[bb + f * 16 + r];
                    x[f][r] = xv;
                    pm = fmaxf(pm, xv);
                }
            pm = fmaxf(pm, __shfl_xor(pm, 16));
            pm = fmaxf(pm, __shfl_xor(pm, 32));

            if (!__all(pm - m_run[ih] <= THR)) {
                float mnew = fmaxf(m_run[ih], pm);
                float corr = __builtin_amdgcn_exp2f(m_run[ih] - mnew);
                m_run[ih] = mnew;
                l_run[ih] *= corr;
                float cb[4];
#pragma unroll
                for (int r = 0; r < 4; ++r) cb[r] = __shfl(corr, lgrp * 4 + r);
#pragma unroll
                for (int n = 0; n < 4; n++)
#pragma unroll
                    for (int r = 0; r < 4; r++) o_acc[ih][n][r] *= cb[r];
            }

            float su = 0.f;
#pragma unroll
            for (int f = 0; f < 4; ++f)
#pragma unroll
                for (int r = 0; r < 4; ++r) {
                    float pv = __builtin_amdgcn_exp2f(x[f][r] - m_run[ih]);
                    x[f][r] = pv;
                    su += pv;
                }
            l_run[ih] += su;

            // ---- P -> Ps section ih (per-wave, swizzled) ----
            unsigned short* psec = &Ps[w][ih * 1024];
#pragma unroll
            for (int f = 0; f < 4; ++f) {
                unsigned int plo, phi;
                asm("v_cvt_pk_bf16_f32 %0, %1, %2"
                    : "=v"(plo)
                    : "v"(x[f][0]), "v"(x[f][1]));
                asm("v_cvt_pk_bf16_f32 %0, %1, %2"
                    : "=v"(phi)
                    : "v"(x[f][2]), "v"(x[f][3]));
                const int chunk = (f * 2 + (lgrp >> 1)) ^ (lrow & 7);
                uint2 pw;
                pw.x = plo;
                pw.y = phi;
                *reinterpret_cast<uint2*>(
                    &psec[lrow * 64 + chunk * 8 + (lgrp & 1) * 4]) = pw;
            }

            // ---- O += P V for slice ih ----
            __builtin_amdgcn_s_setprio(1);
#pragma unroll
            for (int jc = 0; jc < 2; ++jc) {
                int pc = ((4 * jc + lgrp) ^ (lrow & 7)) * 8;
                bf16x8 pa =
                    *reinterpret_cast<const bf16x8*>(psec + lrow * 64 + pc);
#pragma unroll
                for (int n = 0; n < 4; n++) {
                    int vrow = n * 16 + lrow;
                    bf16x8 vb =
                        *reinterpret_cast<const bf16x8*>(vbuf + vrow * 64 + pc);
                    o_acc[ih][n] = MFMA16(pa, vb, o_acc[ih][n]);
                }
            }
            __builtin_amdgcn_s_setprio(0);
        }

        if (kv < 15) {
            asm volatile("s_waitcnt vmcnt(0)" ::: "memory");
            __syncthreads();
        }
    }

    // epilogue per slice
#pragma unroll
    for (int ih = 0; ih < 2; ++ih) {
        float lt = l_run[ih] + __shfl_xor(l_run[ih], 16);
        lt += __shfl_xor(lt, 32);
        float rl[4];
#pragma unroll
        for (int r = 0; r < 4; ++r) rl[r] = 1.0f / __shfl(lt, lgrp * 4 + r);
#pragma unroll
        for (int n = 0; n < 4; n++) {
#pragma unroll
            for (int r = 0; r < 4; r++) {
                float val = o_acc[ih][n][r] * rl[r];
                int ia = qt * 256 + ih * 128 + w * 16 + lgrp * 4 + r;
                size_t m = (size_t)b * 1024 + ia;
                int col = h * 64 + n * 16 + lrow;
                A3[m * 1024 + col] = f2bf(val);
            }
        }
    }
}

extern "C" void kernel_launch(void* const* d_in, const int* in_sizes, int n_in,
                              void* d_out, int out_size, void* d_ws,
                              size_t ws_size, hipStream_t stream) {
    const float* x = (const float*)d_in[0];
    const float* w_qkv = (const float*)d_in[1];
    const float* w_out = (const float*)d_in[2];
    const float* rel_bias = (const float*)d_in[3];
    float* out = (float*)d_out;

    char* ws = (char*)d_ws;
    size_t off = 0;
    auto alloc = [&](size_t bytes) {
        char* p = ws + off;
        off += (bytes + 255) & ~(size_t)255;
        return p;
    };
    unsigned short* A1h = (unsigned short*)alloc((size_t)4096 * 1024 * 2);
    unsigned short* W1h = (unsigned short*)alloc((size_t)3072 * 1024 * 2);
    unsigned short* Qb = (unsigned short*)alloc((size_t)64 * 1024 * 64 * 2);
    unsigned short* Kb = (unsigned short*)alloc((size_t)64 * 1024 * 64 * 2);
    unsigned short* Vb = (unsigned short*)alloc((size_t)64 * 1024 * 64 * 2);
    unsigned short* A3h = (unsigned short*)alloc((size_t)4096 * 1024 * 2);
    unsigned short* W3h = (unsigned short*)alloc((size_t)1024 * 1024 * 2);
    // V^T aliases A1h (8 MB each): A1h dead after gemm256_hi; transpose_v after.
    unsigned short* Vtg = A1h;

    hipLaunchKernelGGL(prep_all, dim3(2048), dim3(256), 0, stream, x, w_qkv,
                       w_out, A1h, W1h, W3h);
    hipLaunchKernelGGL(gemm256_hi, dim3(12, 16), dim3(512), 0, stream, A1h, W1h,
                       Qb, Kb, Vb);
    hipLaunchKernelGGL(transpose_v, dim3(16, 64), dim3(256), 0, stream, Vb, Vtg);
    hipLaunchKernelGGL(attn_kernel, dim3(64, 4), dim3(512), 0, stream, Qb, Kb,
                       Vtg, rel_bias, A3h);
    hipLaunchKernelGGL(gemm_out_v5, dim3(512), dim3(256), 0, stream, A3h, W3h,
                       out);
}

// Round 20
// 97.792 us; speedup vs baseline: 1.0623x; 1.0623x over previous
//
#include <hip/hip_runtime.h>
#include <hip/hip_bf16.h>

typedef short bf16x8 __attribute__((ext_vector_type(8)));
typedef float f32x4  __attribute__((ext_vector_type(4)));

typedef __attribute__((address_space(3))) void lds_t;
typedef __attribute__((address_space(1))) void gbl_t;

#define MFMA16(a,b,c) __builtin_amdgcn_mfma_f32_16x16x32_bf16((a),(b),(c),0,0,0)

__device__ __forceinline__ unsigned short f2bf(float f) {
    __hip_bfloat16 h = __float2bfloat16(f);
    return __builtin_bit_cast(unsigned short, h);
}
__device__ __forceinline__ float bf2f(unsigned short u) {
    __hip_bfloat16 h = __builtin_bit_cast(__hip_bfloat16, u);
    return __bfloat162float(h);
}

// ============================================================================
// Fused prep (R15): x -> A1h, w_qkv (einops permute) -> W1h, w_out -> W3h.
// ============================================================================
__global__ void prep_all(const float* __restrict__ x,
                         const float* __restrict__ w_qkv,
                         const float* __restrict__ w_out,
                         unsigned short* __restrict__ A1h,
                         unsigned short* __restrict__ W1h,
                         unsigned short* __restrict__ W3h) {
    const int NX = 4096 * 256, NW1 = 3072 * 256, NW3 = 1024 * 256;
    for (int idx = blockIdx.x * blockDim.x + threadIdx.x; idx < NX + NW1 + NW3;
         idx += gridDim.x * blockDim.x) {
        if (idx < NX) {
            int base = idx * 4;
            float4 v = *reinterpret_cast<const float4*>(x + base);
            ushort4 hi;
            hi.x = f2bf(v.x); hi.y = f2bf(v.y);
            hi.z = f2bf(v.z); hi.w = f2bf(v.w);
            *reinterpret_cast<ushort4*>(A1h + base) = hi;
        } else if (idx < NX + NW1) {
            int base = (idx - NX) * 4;
            int n = base >> 10, c = base & 1023;
            int d = n & 63, which = n >> 10, h = (n >> 6) & 15;
            int srow = d * 48 + which * 16 + h;
            float4 v =
                *reinterpret_cast<const float4*>(w_qkv + (size_t)srow * 1024 + c);
            ushort4 hi;
            hi.x = f2bf(v.x); hi.y = f2bf(v.y);
            hi.z = f2bf(v.z); hi.w = f2bf(v.w);
            *reinterpret_cast<ushort4*>(W1h + (size_t)n * 1024 + c) = hi;
        } else {
            int base = (idx - NX - NW1) * 4;
            float4 v = *reinterpret_cast<const float4*>(w_out + base);
            ushort4 hi;
            hi.x = f2bf(v.x); hi.y = f2bf(v.y);
            hi.z = f2bf(v.z); hi.w = f2bf(v.w);
            *reinterpret_cast<ushort4*>(W3h + base) = hi;
        }
    }
}

// ============================================================================
// QKV GEMM v6 (R17 — measured ~29us): BK=64, 16 steps, 64 MFMA/step/wave,
// 128KB 2-slot dbuf, XOR swizzle, grid (12,16), 8 waves.
// ============================================================================
__global__ __launch_bounds__(512, 1) void gemm256_hi(
    const unsigned short* __restrict__ A, const unsigned short* __restrict__ B,
    unsigned short* __restrict__ outQ, unsigned short* __restrict__ outK,
    unsigned short* __restrict__ outV) {
    __shared__ unsigned short lds[65536];
    const int tid = threadIdx.x;
    const int wid = tid >> 6, lane = tid & 63;
    const int lrow = lane & 15, lgrp = lane >> 4;
    const int wr = wid >> 2, wc = wid & 3;
    const int mtile = blockIdx.y * 256, ntile = blockIdx.x * 256;

    const int csw0 = (lgrp ^ (lrow & 7)) * 8;
    const int csw1 = ((4 | lgrp) ^ (lrow & 7)) * 8;
    const int arowb = (wr * 128 + lrow) * 64;
    const int browb = (wc * 64 + lrow) * 64;

    const int srow = tid >> 3;
    const int schunk = tid & 7;
    const int gchunk = schunk ^ (srow & 7);
    const unsigned short* Abase = A + (size_t)(mtile + srow) * 1024 + gchunk * 8;
    const unsigned short* Bbase = B + (size_t)(ntile + srow) * 1024 + gchunk * 8;
    const int sdst = srow * 64 + schunk * 8;

    f32x4 acc[8][4];
#pragma unroll
    for (int i = 0; i < 8; ++i)
#pragma unroll
        for (int j = 0; j < 4; ++j) {
            f32x4 z = {0.f, 0.f, 0.f, 0.f};
            acc[i][j] = z;
        }

#pragma unroll
    for (int e = 0; e < 4; ++e)
        __builtin_amdgcn_global_load_lds(
            (const gbl_t*)(Abase + (size_t)e * 64 * 1024),
            (lds_t*)(lds + e * 4096 + sdst), 16, 0, 0);
#pragma unroll
    for (int e = 0; e < 4; ++e)
        __builtin_amdgcn_global_load_lds(
            (const gbl_t*)(Bbase + (size_t)e * 64 * 1024),
            (lds_t*)(lds + 32768 + e * 4096 + sdst), 16, 0, 0);
    asm volatile("s_waitcnt vmcnt(0)" ::: "memory");
    __syncthreads();

    for (int s = 0; s < 16; ++s) {
        const int cur = s & 1;
        const unsigned short* abuf = lds + cur * 16384;
        const unsigned short* bbuf = lds + 32768 + cur * 16384;
        const int nx = cur ^ 1;
        const int kb = (s + 1) * 64;

        if (s < 15) {
#pragma unroll
            for (int e = 0; e < 4; ++e)
                __builtin_amdgcn_global_load_lds(
                    (const gbl_t*)(Abase + (size_t)e * 64 * 1024 + kb),
                    (lds_t*)(lds + nx * 16384 + e * 4096 + sdst), 16, 0, 0);
        }
        {
            bf16x8 af[8], bfv[4];
#pragma unroll
            for (int i = 0; i < 8; ++i)
                af[i] = *reinterpret_cast<const bf16x8*>(abuf + arowb + i * 1024 +
                                                         csw0);
#pragma unroll
            for (int j = 0; j < 4; ++j)
                bfv[j] = *reinterpret_cast<const bf16x8*>(bbuf + browb +
                                                          j * 1024 + csw0);
            __builtin_amdgcn_s_setprio(1);
#pragma unroll
            for (int i = 0; i < 8; ++i)
#pragma unroll
                for (int j = 0; j < 4; ++j)
                    acc[i][j] = MFMA16(af[i], bfv[j], acc[i][j]);
            __builtin_amdgcn_s_setprio(0);
        }
        if (s < 15) {
#pragma unroll
            for (int e = 0; e < 4; ++e)
                __builtin_amdgcn_global_load_lds(
                    (const gbl_t*)(Bbase + (size_t)e * 64 * 1024 + kb),
                    (lds_t*)(lds + 32768 + nx * 16384 + e * 4096 + sdst), 16, 0,
                    0);
        }
        {
            bf16x8 af[8], bfv[4];
#pragma unroll
            for (int i = 0; i < 8; ++i)
                af[i] = *reinterpret_cast<const bf16x8*>(abuf + arowb + i * 1024 +
                                                         csw1);
#pragma unroll
            for (int j = 0; j < 4; ++j)
                bfv[j] = *reinterpret_cast<const bf16x8*>(bbuf + browb +
                                                          j * 1024 + csw1);
            __builtin_amdgcn_s_setprio(1);
#pragma unroll
            for (int i = 0; i < 8; ++i)
#pragma unroll
                for (int j = 0; j < 4; ++j)
                    acc[i][j] = MFMA16(af[i], bfv[j], acc[i][j]);
            __builtin_amdgcn_s_setprio(0);
        }

        if (s < 15) {
            asm volatile("s_waitcnt vmcnt(0)" ::: "memory");
            __syncthreads();
        }
    }

#pragma unroll
    for (int i = 0; i < 8; ++i) {
#pragma unroll
        for (int j = 0; j < 4; ++j) {
#pragma unroll
            for (int r = 0; r < 4; ++r) {
                float v = acc[i][j][r];
                int m = mtile + wr * 128 + i * 16 + lgrp * 4 + r;
                int n = ntile + wc * 64 + j * 16 + lrow;
                int which = n >> 10;
                int hh = (n >> 6) & 15;
                int d = n & 63;
                int b = m >> 10, t = m & 1023;
                unsigned short* dstp =
                    (which == 0) ? outQ : ((which == 1) ? outK : outV);
                dstp[((size_t)((b << 4) + hh) * 1024 + t) * 64 + d] = f2bf(v);
            }
        }
    }
}

// ============================================================================
// Out-projection GEMM v5 (R16 — measured ~14us): BK=64, 16 steps, tile
// 64x128, 4 waves, 2-slot dbuf 48KB, XOR swizzle, XCD swizzle.
// ============================================================================
__global__ __launch_bounds__(256, 3) void gemm_out_v5(
    const unsigned short* __restrict__ A, const unsigned short* __restrict__ B,
    float* __restrict__ outF) {
    __shared__ unsigned short As[2][64 * 64];   // 16 KB
    __shared__ unsigned short Bs[2][128 * 64];  // 32 KB
    const int tid = threadIdx.x;
    const int wid = tid >> 6, lane = tid & 63;
    const int lrow = lane & 15, lgrp = lane >> 4;
    const int wr = wid >> 1, wc = wid & 1;
    const int h = blockIdx.x;
    const int xcd = h & 7, within = h >> 3;
    const int mtile = (xcd * 8 + (within & 7)) * 64;
    const int ntile = (within >> 3) * 128;

    const int srow = tid >> 3;
    const int schunk = (tid & 7) ^ (srow & 7);
    const unsigned short* Abase = A + (size_t)(mtile + srow) * 1024 + schunk * 8;
    const unsigned short* Bbase = B + (size_t)(ntile + srow) * 1024 + schunk * 8;

    const int csw0 = (lgrp ^ (lrow & 7)) * 8;
    const int csw1 = ((4 | lgrp) ^ (lrow & 7)) * 8;
    const int arow = wr * 32 + lrow;
    const int brow = wc * 64 + lrow;

    f32x4 acc[2][4];
#pragma unroll
    for (int i = 0; i < 2; ++i)
#pragma unroll
        for (int j = 0; j < 4; ++j) {
            f32x4 z = {0.f, 0.f, 0.f, 0.f};
            acc[i][j] = z;
        }

#pragma unroll
    for (int e = 0; e < 2; ++e)
        __builtin_amdgcn_global_load_lds(
            (const gbl_t*)(Abase + (size_t)e * 32 * 1024),
            (lds_t*)(&As[0][0] + e * 2048 + tid * 8), 16, 0, 0);
#pragma unroll
    for (int e = 0; e < 4; ++e)
        __builtin_amdgcn_global_load_lds(
            (const gbl_t*)(Bbase + (size_t)e * 32 * 1024),
            (lds_t*)(&Bs[0][0] + e * 2048 + tid * 8), 16, 0, 0);
    asm volatile("s_waitcnt vmcnt(0)" ::: "memory");
    __syncthreads();

    for (int s = 0; s < 16; ++s) {
        const int cur = s & 1;
        if (s < 15) {
            const int kb = (s + 1) * 64;
            const int nx = cur ^ 1;
#pragma unroll
            for (int e = 0; e < 2; ++e)
                __builtin_amdgcn_global_load_lds(
                    (const gbl_t*)(Abase + (size_t)e * 32 * 1024 + kb),
                    (lds_t*)(&As[nx][0] + e * 2048 + tid * 8), 16, 0, 0);
#pragma unroll
            for (int e = 0; e < 4; ++e)
                __builtin_amdgcn_global_load_lds(
                    (const gbl_t*)(Bbase + (size_t)e * 32 * 1024 + kb),
                    (lds_t*)(&Bs[nx][0] + e * 2048 + tid * 8), 16, 0, 0);
        }
        bf16x8 a0[2], a1[2], b0[4], b1[4];
#pragma unroll
        for (int i = 0; i < 2; ++i) {
            a0[i] = *reinterpret_cast<const bf16x8*>(&As[cur][0] +
                                                     (arow + i * 16) * 64 + csw0);
            a1[i] = *reinterpret_cast<const bf16x8*>(&As[cur][0] +
                                                     (arow + i * 16) * 64 + csw1);
        }
#pragma unroll
        for (int j = 0; j < 4; ++j) {
            b0[j] = *reinterpret_cast<const bf16x8*>(&Bs[cur][0] +
                                                     (brow + j * 16) * 64 + csw0);
            b1[j] = *reinterpret_cast<const bf16x8*>(&Bs[cur][0] +
                                                     (brow + j * 16) * 64 + csw1);
        }
        __builtin_amdgcn_s_setprio(1);
#pragma unroll
        for (int i = 0; i < 2; ++i)
#pragma unroll
            for (int j = 0; j < 4; ++j) {
                acc[i][j] = MFMA16(a0[i], b0[j], acc[i][j]);
                acc[i][j] = MFMA16(a1[i], b1[j], acc[i][j]);
            }
        __builtin_amdgcn_s_setprio(0);
        if (s < 15) {
            asm volatile("s_waitcnt vmcnt(0)" ::: "memory");
            __syncthreads();
        }
    }

#pragma unroll
    for (int i = 0; i < 2; ++i)
#pragma unroll
        for (int j = 0; j < 4; ++j)
#pragma unroll
            for (int r = 0; r < 4; ++r) {
                int m = mtile + wr * 32 + i * 16 + lgrp * 4 + r;
                int n = ntile + wc * 64 + j * 16 + lrow;
                outF[(size_t)m * 1024 + n] = acc[i][j][r];
            }
}

// V [bh][1024][64] -> V^T [bh][64][1024], LDS-tiled, coalesced both sides.
__global__ __launch_bounds__(256) void transpose_v(
    const unsigned short* __restrict__ Vb, unsigned short* __restrict__ Vtg) {
    __shared__ unsigned short L[64][72];
    const int tt = blockIdx.x, bh = blockIdx.y;
    const int tid = threadIdx.x;
#pragma unroll
    for (int e = 0; e < 2; ++e) {
        int chunk = e * 256 + tid;
        int r = chunk >> 3, c = (chunk & 7) * 8;
        uint4 v = *reinterpret_cast<const uint4*>(
            Vb + ((size_t)bh * 1024 + tt * 64 + r) * 64 + c);
        *reinterpret_cast<uint4*>(&L[r][c]) = v;
    }
    __syncthreads();
#pragma unroll
    for (int e = 0; e < 2; ++e) {
        int chunk = e * 256 + tid;
        int d = chunk >> 3, t0 = (chunk & 7) * 8;
        unsigned short tmp[8];
#pragma unroll
        for (int u = 0; u < 8; ++u) tmp[u] = L[t0 + u][d];
        *reinterpret_cast<uint4*>(Vtg + ((size_t)bh * 64 + d) * 1024 + tt * 64 +
                                  t0) = *reinterpret_cast<const uint4*>(tmp);
    }
}

// ============================================================================
// Flash attention — EXACT R18 (measured best ~33us): QBLK=128, 8 waves,
// grid (64,8) XCD-local (flat = bh + 64*qt -> XCD = bh%8), one-time bias
// stage, swapped QK^T, exp2 softmax, defer-max, cvt_pk P-pack, K/V dbuf.
// R19 lesson: QBLK=256 (256 blocks = 1/CU) lost co-residency -> +10us despite
// 5x less FETCH.  Never trade co-residency for per-step work.
// ============================================================================
__global__ __launch_bounds__(512) void attn_kernel(
    const unsigned short* __restrict__ Qb, const unsigned short* __restrict__ Kb,
    const unsigned short* __restrict__ Vtg, const float* __restrict__ rel_bias,
    unsigned short* __restrict__ A3) {
    const int bh = blockIdx.x;  // 0..63  (XCD = bh%8)
    const int qt = blockIdx.y;  // 0..7 (128 q-rows each)
    const int b = bh >> 4, h = bh & 15;
    const int tid = threadIdx.x;
    const int w = tid >> 6, lane = tid & 63;  // w in 0..7
    const int lrow = lane & 15, lgrp = lane >> 4;
    const float LOG2E = 1.4426950408889634f;
    const float SCALE2 = 0.125f * 1.4426950408889634f;
    const float THR = 11.5f;  // ~8 nats in exp2 units

    __shared__ unsigned short Ks[2][64 * 64];  // 16 KB
    __shared__ unsigned short Vs[2][64 * 64];  // 16 KB
    __shared__ unsigned short Ps[8][16 * 64];  // 16 KB
    __shared__ float BiasF[1152];              // 4.5 KB, staged once

    const unsigned short* Ktile = Kb + (size_t)bh * 1024 * 64;
    const unsigned short* Vtile = Vtg + (size_t)bh * 64 * 1024;

    const unsigned short* Qp =
        Qb + ((size_t)bh * 1024 + qt * 128 + w * 16 + lrow) * 64;
    bf16x8 qa0 = *reinterpret_cast<const bf16x8*>(Qp + lgrp * 8);
    bf16x8 qa1 = *reinterpret_cast<const bf16x8*>(Qp + 32 + lgrp * 8);

    const int sr0 = w * 8 + (lane >> 3);
    const int sc_lo = lane & 7;

    float m_run = -3.0e38f;
    float l_run = 0.f;
    f32x4 o_acc[4];
#pragma unroll
    for (int n = 0; n < 4; n++) {
        f32x4 z = {0.f, 0.f, 0.f, 0.f};
        o_acc[n] = z;
    }

    const int bbase = lgrp * 4 + 127 - w * 16 - lrow;

    {
        {
            int r = sr0;
            int c = sc_lo ^ (r & 7);
            __builtin_amdgcn_global_load_lds(
                (const gbl_t*)(Ktile + (size_t)r * 64 + c * 8),
                (lds_t*)(&Ks[0][0] + w * 512), 16, 0, 0);
            __builtin_amdgcn_global_load_lds(
                (const gbl_t*)(Vtile + (size_t)r * 1024 + c * 8),
                (lds_t*)(&Vs[0][0] + w * 512), 16, 0, 0);
        }
        const int rbase = 896 - qt * 128;
        for (int t = tid; t < 1151; t += 512)
            BiasF[t] = rel_bias[(size_t)(t + rbase) * 16 + h] * LOG2E;
        asm volatile("s_waitcnt vmcnt(0)" ::: "memory");
        __syncthreads();
    }

    for (int kv = 0; kv < 16; ++kv) {
        const int cur = kv & 1;
        const int j0 = kv * 64;
        if (kv < 15) {
            const int j0n = (kv + 1) * 64;
            int r = sr0;
            int c = sc_lo ^ (r & 7);
            __builtin_amdgcn_global_load_lds(
                (const gbl_t*)(Ktile + (size_t)(j0n + r) * 64 + c * 8),
                (lds_t*)(&Ks[cur ^ 1][0] + w * 512), 16, 0, 0);
            __builtin_amdgcn_global_load_lds(
                (const gbl_t*)(Vtile + (size_t)r * 1024 + j0n + c * 8),
                (lds_t*)(&Vs[cur ^ 1][0] + w * 512), 16, 0, 0);
        }

        const unsigned short* kbuf = &Ks[cur][0];
        f32x4 s[4];
        __builtin_amdgcn_s_setprio(1);
#pragma unroll
        for (int f = 0; f < 4; ++f) {
            int krow = f * 16 + lrow;
            int sw0 = (lgrp ^ (lrow & 7)) * 8;
            int sw1 = ((4 | lgrp) ^ (lrow & 7)) * 8;
            bf16x8 kb0 = *reinterpret_cast<const bf16x8*>(kbuf + krow * 64 + sw0);
            bf16x8 kb1 = *reinterpret_cast<const bf16x8*>(kbuf + krow * 64 + sw1);
            f32x4 z = {0.f, 0.f, 0.f, 0.f};
            z = MFMA16(kb0, qa0, z);
            z = MFMA16(kb1, qa1, z);
            s[f] = z;
        }
        __builtin_amdgcn_s_setprio(0);

        float x[4][4];
        float pm = -3.0e38f;
#pragma unroll
        for (int f = 0; f < 4; ++f)
#pragma unroll
            for (int r = 0; r < 4; ++r) {
                float xv = s[f][r] * SCALE2 + BiasF[j0 + bbase + f * 16 + r];
                x[f][r] = xv;
                pm = fmaxf(pm, xv);
            }
        pm = fmaxf(pm, __shfl_xor(pm, 16));
        pm = fmaxf(pm, __shfl_xor(pm, 32));

        if (!__all(pm - m_run <= THR)) {
            float mnew = fmaxf(m_run, pm);
            float corr = __builtin_amdgcn_exp2f(m_run - mnew);
            m_run = mnew;
            l_run *= corr;
            float cb[4];
#pragma unroll
            for (int r = 0; r < 4; ++r) cb[r] = __shfl(corr, lgrp * 4 + r);
#pragma unroll
            for (int n = 0; n < 4; n++)
#pragma unroll
                for (int r = 0; r < 4; r++) o_acc[n][r] *= cb[r];
        }

        float su = 0.f;
#pragma unroll
        for (int f = 0; f < 4; ++f)
#pragma unroll
            for (int r = 0; r < 4; ++r) {
                float pv = __builtin_amdgcn_exp2f(x[f][r] - m_run);
                x[f][r] = pv;
                su += pv;
            }
        l_run += su;

#pragma unroll
        for (int f = 0; f < 4; ++f) {
            unsigned int plo, phi;
            asm("v_cvt_pk_bf16_f32 %0, %1, %2"
                : "=v"(plo)
                : "v"(x[f][0]), "v"(x[f][1]));
            asm("v_cvt_pk_bf16_f32 %0, %1, %2"
                : "=v"(phi)
                : "v"(x[f][2]), "v"(x[f][3]));
            const int chunk = (f * 2 + (lgrp >> 1)) ^ (lrow & 7);
            uint2 pw;
            pw.x = plo;
            pw.y = phi;
            *reinterpret_cast<uint2*>(
                &Ps[w][lrow * 64 + chunk * 8 + (lgrp & 1) * 4]) = pw;
        }

        const unsigned short* vbuf = &Vs[cur][0];
        __builtin_amdgcn_s_setprio(1);
#pragma unroll
        for (int jc = 0; jc < 2; ++jc) {
            int pc = ((4 * jc + lgrp) ^ (lrow & 7)) * 8;
            bf16x8 pa =
                *reinterpret_cast<const bf16x8*>(&Ps[w][0] + lrow * 64 + pc);
#pragma unroll
            for (int n = 0; n < 4; n++) {
                int vrow = n * 16 + lrow;
                bf16x8 vb =
                    *reinterpret_cast<const bf16x8*>(vbuf + vrow * 64 + pc);
                o_acc[n] = MFMA16(pa, vb, o_acc[n]);
            }
        }
        __builtin_amdgcn_s_setprio(0);

        if (kv < 15) {
            asm volatile("s_waitcnt vmcnt(0)" ::: "memory");
            __syncthreads();
        }
    }

    float lt = l_run + __shfl_xor(l_run, 16);
    lt += __shfl_xor(lt, 32);
    float rl[4];
#pragma unroll
    for (int r = 0; r < 4; ++r) rl[r] = 1.0f / __shfl(lt, lgrp * 4 + r);

    // compact hi-only epilogue
#pragma unroll
    for (int n = 0; n < 4; n++) {
#pragma unroll
        for (int r = 0; r < 4; r++) {
            float val = o_acc[n][r] * rl[r];
            int ia = qt * 128 + w * 16 + lgrp * 4 + r;
            size_t m = (size_t)b * 1024 + ia;
            int col = h * 64 + n * 16 + lrow;
            A3[m * 1024 + col] = f2bf(val);
        }
    }
}

extern "C" void kernel_launch(void* const* d_in, const int* in_sizes, int n_in,
                              void* d_out, int out_size, void* d_ws,
                              size_t ws_size, hipStream_t stream) {
    const float* x = (const float*)d_in[0];
    const float* w_qkv = (const float*)d_in[1];
    const float* w_out = (const float*)d_in[2];
    const float* rel_bias = (const float*)d_in[3];
    float* out = (float*)d_out;

    char* ws = (char*)d_ws;
    size_t off = 0;
    auto alloc = [&](size_t bytes) {
        char* p = ws + off;
        off += (bytes + 255) & ~(size_t)255;
        return p;
    };
    unsigned short* A1h = (unsigned short*)alloc((size_t)4096 * 1024 * 2);
    unsigned short* W1h = (unsigned short*)alloc((size_t)3072 * 1024 * 2);
    unsigned short* Qb = (unsigned short*)alloc((size_t)64 * 1024 * 64 * 2);
    unsigned short* Kb = (unsigned short*)alloc((size_t)64 * 1024 * 64 * 2);
    unsigned short* Vb = (unsigned short*)alloc((size_t)64 * 1024 * 64 * 2);
    unsigned short* A3h = (unsigned short*)alloc((size_t)4096 * 1024 * 2);
    unsigned short* W3h = (unsigned short*)alloc((size_t)1024 * 1024 * 2);
    // V^T aliases A1h (8 MB each): A1h dead after gemm256_hi; transpose_v after.
    unsigned short* Vtg = A1h;

    hipLaunchKernelGGL(prep_all, dim3(2048), dim3(256), 0, stream, x, w_qkv,
                       w_out, A1h, W1h, W3h);
    hipLaunchKernelGGL(gemm256_hi, dim3(12, 16), dim3(512), 0, stream, A1h, W1h,
                       Qb, Kb, Vb);
    hipLaunchKernelGGL(transpose_v, dim3(16, 64), dim3(256), 0, stream, Vb, Vtg);
    hipLaunchKernelGGL(attn_kernel, dim3(64, 8), dim3(512), 0, stream, Qb, Kb,
                       Vtg, rel_bias, A3h);
    hipLaunchKernelGGL(gemm_out_v5, dim3(512), dim3(256), 0, stream, A3h, W3h,
                       out);
}